// Round 6
// baseline (14327.394 us; speedup 1.0000x reference)
//
#include <hip/hip_runtime.h>
#include <math.h>

#define B_   256
#define E_   304
#define H_   304
#define T_   512
#define P_   68
#define PD   67      // decoder output positions
#define D_   61
#define NCB  16      // col-blocks per batch group
#define NBG  32      // batch groups
#define RB   8       // rows (batch) per block
#define CBH  19      // h-cols per block
#define GC   57      // gate-cols per block (3*19)
#define KCW  76      // k-chunk per wave (304/4)
#define NSTEP (T_ + PD)
#define HW   152     // ull words per h/x row (304 floats)
#define BLK_ULL (RB * HW)   // 1216
#define ARRV_PER_STEP (NCB * 4)   // 64 wave-arrivals per group per step

typedef unsigned long long ull;
typedef float v2f __attribute__((ext_vector_type(2)));

// partials; inner pad 9 (odd stride -> bank spread). red0 double-buffered.
#define RED0(b, k, cc, rr) lds_red0[((((b)*4 + (k))*GC) + (cc))*9 + (rr)]
#define RED1(k, cc, rr)    lds_red1[(((k)*GC) + (cc))*9 + (rr)]

// ---------------------------------------------------------------------------
// Persistent GRU, 2 blocks/CU, 2 __syncthreads per step.
// Grid 512 blocks of 256 thr. Linear block id L remapped so the 16 col-blocks
// of a batch group share one XCD (L%8): xcd=L&7, cb=(L>>3)&15, bg=(L>>7)*8+xcd.
// Block (cb,bg): rows r0=bg*8..+7, h-cols c0h=cb*19..+18 (57 gate-cols).
// Thread (kc=wave, lane<57): Wih+Whh k-chunk for ONE gate-col, as v2f pairs
// feeding v_pk_fma_f32.
// Per step s (wave-level; xs/hs/red0 double-buffered by parity):
//   [s==T_: reload wh] | spin ctr>=64*s | issue h(s) loads | xs[(s+1)&1]<-xr |
//   issue xr<-x(s+2) | hs[s&1]<-hreg | syncA | gh GEMM -> red1 | syncB |
//   gates -> h(s+1) agent-store (+dec_outs) | lane0: ctr+=1 (RELEASE) |
//   [s+1==T_: reload wi] | gi(s+1) -> red0[(s+1)&1]  (hides in peer skew)
// ---------------------------------------------------------------------------
__global__ __launch_bounds__(256, 2) void gru_persist(
    const float* __restrict__ input,   // [B][T][E]
    const int*   __restrict__ target,  // [B][P]
    const float* __restrict__ emb,     // [D][E]
    const float* __restrict__ eWih, const float* __restrict__ eWhh,
    const float* __restrict__ ebih, const float* __restrict__ ebhh,
    const float* __restrict__ dWih, const float* __restrict__ dWhh,
    const float* __restrict__ dbih, const float* __restrict__ dbhh,
    float* hbuf,                       // [2][B*H]
    float* __restrict__ dec_outs,      // [(b*PD+p)*H]
    int* ctr)                          // [NBG*32]
{
    __shared__ float xs[2][RB][H_];
    __shared__ float hs[2][RB][H_];
    __shared__ float lds_red0[2 * 4 * GC * 9];
    __shared__ float lds_red1[4 * GC * 9];
    __shared__ float bi_l[2][GC], bh_l[2][GC];

    const int tid  = threadIdx.x;
    const int L    = blockIdx.y * NCB + blockIdx.x;   // 0..511
    const int xcd  = L & 7;
    const int yy   = L >> 3;
    const int cb   = yy & 15;                          // 0..15
    const int bg   = ((yy >> 4) << 3) | xcd;           // 0..31, group on one XCD
    const int r0   = bg * RB;
    const int c0h  = cb * CBH;
    const int kc   = tid >> 6;         // wave id = k-chunk
    const int lane = tid & 63;
    const bool act = lane < GC;
    int* ctrp = ctr + bg * 32;

    v2f wi2[38], wh2[38];

    auto load_wi = [&](const float* Wih) {
        if (act) {
            int g = lane / CBH, j = lane - (lane / CBH) * CBH;
            const float* pi = Wih + (size_t)(g * H_ + c0h + j) * E_ + kc * KCW;
            #pragma unroll
            for (int q = 0; q < 19; ++q) {
                float4 v = *(const float4*)(pi + 4 * q);
                v2f a; a.x = v.x; a.y = v.y;
                v2f b; b.x = v.z; b.y = v.w;
                wi2[2 * q] = a; wi2[2 * q + 1] = b;
            }
        }
    };
    auto load_wh = [&](const float* Whh) {
        if (act) {
            int g = lane / CBH, j = lane - (lane / CBH) * CBH;
            const float* ph = Whh + (size_t)(g * H_ + c0h + j) * H_ + kc * KCW;
            #pragma unroll
            for (int q = 0; q < 19; ++q) {
                float4 v = *(const float4*)(ph + 4 * q);
                v2f a; a.x = v.x; a.y = v.y;
                v2f b; b.x = v.z; b.y = v.w;
                wh2[2 * q] = a; wh2[2 * q + 1] = b;
            }
        }
    };

    load_wi(eWih);
    load_wh(eWhh);
    // biases for BOTH phases staged up front (no mid-run LDS overwrite race)
    if (tid < GC) {
        int g = tid / CBH, j = tid - (tid / CBH) * CBH;
        bi_l[0][tid] = ebih[g * H_ + c0h + j];
        bh_l[0][tid] = ebhh[g * H_ + c0h + j];
        bi_l[1][tid] = dbih[g * H_ + c0h + j];
        bh_l[1][tid] = dbhh[g * H_ + c0h + j];
    }

    // ---- prologue: xs[0] <- x(0) ----
    {
        const ull* xin = (const ull*)input;
        #pragma unroll
        for (int i = 0; i < 5; ++i) {
            int f = tid + 256 * i;
            if (i < 4 || f < BLK_ULL) {
                int rr = f / HW, q = f - (f / HW) * HW;
                ((ull*)xs[0])[f] = xin[(size_t)(r0 + rr) * T_ * HW + q];
            }
        }
    }
    __syncthreads();
    // gi(0) -> red0[0]
    if (act) {
        #pragma unroll 4
        for (int rr = 0; rr < RB; ++rr) {
            v2f a0 = {0.f, 0.f}, a1 = {0.f, 0.f};
            #pragma unroll
            for (int q = 0; q < 19; ++q) {
                float4 xv = *(const float4*)&xs[0][rr][kc * KCW + 4 * q];
                v2f lo; lo.x = xv.x; lo.y = xv.y;
                v2f hi; hi.x = xv.z; hi.y = xv.w;
                a0 = __builtin_elementwise_fma(lo, wi2[2 * q],     a0);
                a1 = __builtin_elementwise_fma(hi, wi2[2 * q + 1], a1);
            }
            v2f a = a0 + a1;
            RED0(0, kc, lane, rr) = a.x + a.y;
        }
    }
    // xr <- x(1)
    ull xr[5];
    {
        const ull* xin = (const ull*)input;
        #pragma unroll
        for (int i = 0; i < 5; ++i) {
            int f = tid + 256 * i;
            if (i < 4 || f < BLK_ULL) {
                int rr = f / HW, q = f - (f / HW) * HW;
                xr[i] = xin[((size_t)(r0 + rr) * T_ + 1) * HW + q];
            }
        }
    }

    for (int s = 0; s < NSTEP; ++s) {
        const bool enc = (s < T_);
        if (s == T_) load_wh(dWhh);            // private regs, race-free

        // ---- per-wave spin: all blocks' h(s) stores complete ----
        if (s > 0) {
            int tgt = ARRV_PER_STEP * s;
            while (__hip_atomic_load(ctrp, __ATOMIC_RELAXED,
                                     __HIP_MEMORY_SCOPE_AGENT) < tgt)
                __builtin_amdgcn_s_sleep(1);
        }
        // ---- issue h(s) loads ----
        ull hreg[5];
        if (s > 0) {
            const ull* hsrc = (const ull*)(hbuf + (size_t)(s & 1) * (B_ * H_))
                              + (size_t)r0 * HW;
            #pragma unroll
            for (int i = 0; i < 5; ++i) {
                int f = tid + 256 * i;
                if (i < 4 || f < BLK_ULL)
                    hreg[i] = __hip_atomic_load(hsrc + f, __ATOMIC_RELAXED,
                                                __HIP_MEMORY_SCOPE_AGENT);
            }
        }
        // ---- xs[(s+1)&1] <- xr (= x(s+1)) ----
        if (s + 1 < NSTEP) {
            ull* xd = (ull*)xs[(s + 1) & 1];
            #pragma unroll
            for (int i = 0; i < 5; ++i) {
                int f = tid + 256 * i;
                if (i < 4 || f < BLK_ULL) xd[f] = xr[i];
            }
        }
        // ---- issue xr <- x(s+2) ----
        if (s + 2 < NSTEP) {
            if (s + 2 < T_) {
                const ull* xin = (const ull*)input;
                #pragma unroll
                for (int i = 0; i < 5; ++i) {
                    int f = tid + 256 * i;
                    if (i < 4 || f < BLK_ULL) {
                        int rr = f / HW, q = f - (f / HW) * HW;
                        xr[i] = xin[((size_t)(r0 + rr) * T_ + (s + 2)) * HW + q];
                    }
                }
            } else {
                const ull* eb = (const ull*)emb;
                int p2 = s + 2 - T_;
                #pragma unroll
                for (int i = 0; i < 5; ++i) {
                    int f = tid + 256 * i;
                    if (i < 4 || f < BLK_ULL) {
                        int rr = f / HW, q = f - (f / HW) * HW;
                        int tok = (p2 == 0) ? 0 : target[(r0 + rr) * P_ + p2];
                        xr[i] = eb[(size_t)tok * HW + q];
                    }
                }
            }
        }
        // ---- hs[s&1] <- hreg (or zeros at s=0) ----
        {
            ull* hd = (ull*)hs[s & 1];
            if (s > 0) {
                #pragma unroll
                for (int i = 0; i < 5; ++i) {
                    int f = tid + 256 * i;
                    if (i < 4 || f < BLK_ULL) hd[f] = hreg[i];
                }
            } else {
                #pragma unroll
                for (int i = 0; i < 5; ++i) {
                    int f = tid + 256 * i;
                    if (i < 4 || f < BLK_ULL) hd[f] = 0ull;
                }
            }
        }
        __syncthreads();   // A: hs[s&1] ready (red0[s&1] ready since prev iter)

        // ---- gh GEMM: h(s) . Whh -> red1 ----
        if (act) {
            #pragma unroll 4
            for (int rr = 0; rr < RB; ++rr) {
                v2f a0 = {0.f, 0.f}, a1 = {0.f, 0.f};
                #pragma unroll
                for (int q = 0; q < 19; ++q) {
                    float4 hv = *(const float4*)&hs[s & 1][rr][kc * KCW + 4 * q];
                    v2f lo; lo.x = hv.x; lo.y = hv.y;
                    v2f hi; hi.x = hv.z; hi.y = hv.w;
                    a0 = __builtin_elementwise_fma(lo, wh2[2 * q],     a0);
                    a1 = __builtin_elementwise_fma(hi, wh2[2 * q + 1], a1);
                }
                v2f a = a0 + a1;
                RED1(kc, lane, rr) = a.x + a.y;
            }
        }
        __syncthreads();   // B: red1 ready

        // ---- gates -> h(s+1) ----
        float* hdst = hbuf + (size_t)((s + 1) & 1) * (B_ * H_);
        if (tid < RB * CBH) {
            int rr = tid / CBH, j = tid - (tid / CBH) * CBH;
            int col = c0h + j;
            int ph = enc ? 0 : 1;
            float Gi[3], Gh[3];
            #pragma unroll
            for (int g = 0; g < 3; ++g) {
                int cc = g * CBH + j;
                Gi[g] = RED0(s & 1, 0, cc, rr) + RED0(s & 1, 1, cc, rr) +
                        RED0(s & 1, 2, cc, rr) + RED0(s & 1, 3, cc, rr) +
                        bi_l[ph][cc];
                Gh[g] = RED1(0, cc, rr) + RED1(1, cc, rr) +
                        RED1(2, cc, rr) + RED1(3, cc, rr) + bh_l[ph][cc];
            }
            float rg = 1.f / (1.f + expf(-(Gi[0] + Gh[0])));
            float zg = 1.f / (1.f + expf(-(Gi[1] + Gh[1])));
            float ng = tanhf(Gi[2] + rg * Gh[2]);
            float hnew = (1.f - zg) * ng + zg * hs[s & 1][rr][col];
            __hip_atomic_store(&hdst[(size_t)(r0 + rr) * H_ + col], hnew,
                               __ATOMIC_RELAXED, __HIP_MEMORY_SCOPE_AGENT);
            if (!enc)
                dec_outs[((size_t)(r0 + rr) * PD + (s - T_)) * H_ + col] = hnew;
        }

        if (s + 1 < NSTEP) {
            // per-wave arrival; RELEASE drains this wave's h stores first
            if (lane == 0)
                __hip_atomic_fetch_add(ctrp, 1, __ATOMIC_RELEASE,
                                       __HIP_MEMORY_SCOPE_AGENT);
            if (s + 1 == T_) load_wi(dWih);    // private regs, race-free
            // ---- gi(s+1): x(s+1) . Wih -> red0[(s+1)&1] (hides peer skew) ----
            if (act) {
                #pragma unroll 4
                for (int rr = 0; rr < RB; ++rr) {
                    v2f a0 = {0.f, 0.f}, a1 = {0.f, 0.f};
                    #pragma unroll
                    for (int q = 0; q < 19; ++q) {
                        float4 xv = *(const float4*)&xs[(s + 1) & 1][rr][kc * KCW + 4 * q];
                        v2f lo; lo.x = xv.x; lo.y = xv.y;
                        v2f hi; hi.x = xv.z; hi.y = xv.w;
                        a0 = __builtin_elementwise_fma(lo, wi2[2 * q],     a0);
                        a1 = __builtin_elementwise_fma(hi, wi2[2 * q + 1], a1);
                    }
                    v2f a = a0 + a1;
                    RED0((s + 1) & 1, kc, lane, rr) = a.x + a.y;
                }
            }
        }
    }
}

// ---------------------------------------------------------------------------
// logits -> softmax -> (softmax_cal, target_cal, asr_outputs)
// ---------------------------------------------------------------------------
__global__ __launch_bounds__(256) void logits_softmax(
    const float* __restrict__ dec_outs,   // [B*PD][H]
    const float* __restrict__ linW,       // [61][304]
    const float* __restrict__ linb,       // [61]
    const int* __restrict__ target,       // [B][P][1]
    float* __restrict__ out)
{
    __shared__ float wsm[H_][64];   // transposed W
    __shared__ float rs[4][H_];
    const int tid = threadIdx.x;
    const int wv = tid >> 6, l = tid & 63;

    for (int f = tid; f < H_ * 64; f += 256) {
        int k = f >> 6, ll = f & 63;
        wsm[k][ll] = (ll < D_) ? linW[(size_t)ll * H_ + k] : 0.f;
    }
    const int r = blockIdx.x * 4 + wv;
    const float* rowp = dec_outs + (size_t)r * H_;
    for (int k = l; k < H_; k += 64) rs[wv][k] = rowp[k];
    __syncthreads();

    float acc = -1e30f;
    if (l < D_) {
        acc = linb[l];
        #pragma unroll 4
        for (int k = 0; k < H_; ++k) acc += rs[wv][k] * wsm[k][l];
    }
    float m = acc;
    for (int off = 32; off; off >>= 1) m = fmaxf(m, __shfl_xor(m, off));
    float e = (l < D_) ? expf(acc - m) : 0.f;
    float s = e;
    for (int off = 32; off; off >>= 1) s += __shfl_xor(s, off);
    float av = acc; int ai = l;
    for (int off = 32; off; off >>= 1) {
        float ov = __shfl_xor(av, off);
        int oi = __shfl_xor(ai, off);
        if (ov > av || (ov == av && oi < ai)) { av = ov; ai = oi; }
    }
    const int b = r / PD, p = r - (r / PD) * PD;
    const size_t OFF1 = (size_t)B_ * PD * D_;
    const size_t OFF2 = OFF1 + (size_t)B_ * PD;
    if (l < D_)        out[(size_t)r * D_ + l] = e / s;
    else if (l == D_)  out[OFF1 + r] = (float)target[b * P_ + p + 1];
    else if (l == D_ + 1) out[OFF2 + r] = (float)ai;
}

// ---------------------------------------------------------------------------
extern "C" void kernel_launch(void* const* d_in, const int* in_sizes, int n_in,
                              void* d_out, int out_size, void* d_ws, size_t ws_size,
                              hipStream_t stream)
{
    const float* input  = (const float*)d_in[0];
    const int*   target = (const int*)d_in[1];
    const float* eWih = (const float*)d_in[3];
    const float* eWhh = (const float*)d_in[4];
    const float* ebih = (const float*)d_in[5];
    const float* ebhh = (const float*)d_in[6];
    const float* emb  = (const float*)d_in[7];
    const float* dWih = (const float*)d_in[8];
    const float* dWhh = (const float*)d_in[9];
    const float* dbih = (const float*)d_in[10];
    const float* dbhh = (const float*)d_in[11];
    const float* linW = (const float*)d_in[12];
    const float* linb = (const float*)d_in[13];
    float* out = (float*)d_out;

    int*   ctr      = (int*)d_ws;                    // NBG*32 ints (4 KB)
    float* hbuf     = (float*)d_ws + 1024;           // 2 * B*H
    float* dec_outs = hbuf + 2 * (size_t)B_ * H_;    // B*PD*H

    (void)hipMemsetAsync(ctr, 0, 1024 * sizeof(int), stream);

    gru_persist<<<dim3(NCB, NBG), 256, 0, stream>>>(
        input, target, emb,
        eWih, eWhh, ebih, ebhh,
        dWih, dWhh, dbih, dbhh,
        hbuf, dec_outs, ctr);

    logits_softmax<<<dim3(B_ * PD / 4), 256, 0, stream>>>(
        dec_outs, linW, linb, target, out);
}

// Round 7
// 6789.169 us; speedup vs baseline: 2.1103x; 2.1103x over previous
//
#include <hip/hip_runtime.h>
#include <math.h>

#define B_   256
#define E_   304
#define H_   304
#define T_   512
#define P_   68
#define PD   67      // decoder output positions
#define D_   61
#define NCB  16      // col-blocks per batch group
#define NBG  32      // batch groups
#define RB   8       // rows (batch) per block
#define CBH  19      // h-cols per block
#define GC   57      // gate-cols per block (3*19)
#define KCW  76      // k-chunk per wave (304/4)
#define NSTEP (T_ + PD)
#define HW   152     // ull words per h/x row (304 floats)
#define BLK_ULL (RB * HW)   // 1216

typedef unsigned long long ull;
typedef float v2f __attribute__((ext_vector_type(2)));

// partials: red[m][kc][cc][rr], inner pad 9 (odd stride -> bank spread)
#define RED(m, kc, cc, rr) lds_red[(((m)*4 + (kc))*GC + (cc))*9 + (rr)]

// ---------------------------------------------------------------------------
// Persistent GRU, 2 blocks/CU. Grid (16,32)=512 blocks, 256 thr.
// Linear block id L remapped so a batch group's 16 col-blocks share one XCD
// (round-robin dispatch assumption): xcd=L&7, cb=(L>>3)&15, bg=(L>>7)*8+xcd.
// Block (cb,bg): rows r0=bg*8..+7, h-cols c0h=cb*19..+18 (57 gate-cols).
// Thread (kc=wave, lane<57): Wih+Whh k-chunk for ONE gate-col as v2f pairs
// (v_pk_fma_f32 datapath), 152 weight floats/thread (VGPR+AGPR, no spill).
// Per step s (R5-verified sync structure, 4 __syncthreads):
//   top-sync | [s==T_: wh<-dec] | issue h(s) loads | xs<-xr | issue xr<-x(s+2)
//   | hs<-hreg | mid-sync | gh GEMM -> red1 | red-sync | gates -> h(s+1)
//   agent-store (+dec_outs) | drain-sync | tid0 arrive (RELAXED; drain-sync
//   already flushed stores) | [s+1==T_: wi<-dec] | gi(s+1) -> red0 (hides in
//   peer skew) | tid0 spin
// ---------------------------------------------------------------------------
__global__ __launch_bounds__(256, 2) void gru_persist(
    const float* __restrict__ input,   // [B][T][E]
    const int*   __restrict__ target,  // [B][P]
    const float* __restrict__ emb,     // [D][E]
    const float* __restrict__ eWih, const float* __restrict__ eWhh,
    const float* __restrict__ ebih, const float* __restrict__ ebhh,
    const float* __restrict__ dWih, const float* __restrict__ dWhh,
    const float* __restrict__ dbih, const float* __restrict__ dbhh,
    float* hbuf,                       // [2][B*H]
    float* __restrict__ dec_outs,      // [(b*PD+p)*H]
    int* ctr)                          // [NBG*32]
{
    __shared__ float xs[RB][H_];
    __shared__ float hs[RB][H_];
    __shared__ float lds_red[2 * 4 * GC * 9];
    __shared__ float bi_l[2][GC], bh_l[2][GC];

    const int tid  = threadIdx.x;
    const int L    = blockIdx.y * NCB + blockIdx.x;   // 0..511
    const int xcd  = L & 7;
    const int yy   = L >> 3;
    const int cb   = yy & 15;                          // 0..15
    const int bg   = ((yy >> 4) << 3) | xcd;           // 0..31, group on one XCD
    const int r0   = bg * RB;
    const int c0h  = cb * CBH;
    const int kc   = tid >> 6;         // wave id = k-chunk
    const int lane = tid & 63;
    const bool act = lane < GC;
    int* ctrp = ctr + bg * 32;

    v2f wi2[38], wh2[38];

    auto load_wi = [&](const float* Wih) {
        if (act) {
            int g = lane / CBH, j = lane - (lane / CBH) * CBH;
            const float* pi = Wih + (size_t)(g * H_ + c0h + j) * E_ + kc * KCW;
            #pragma unroll
            for (int q = 0; q < 19; ++q) {
                float4 v = *(const float4*)(pi + 4 * q);
                v2f a; a.x = v.x; a.y = v.y;
                v2f b; b.x = v.z; b.y = v.w;
                wi2[2 * q] = a; wi2[2 * q + 1] = b;
            }
        }
    };
    auto load_wh = [&](const float* Whh) {
        if (act) {
            int g = lane / CBH, j = lane - (lane / CBH) * CBH;
            const float* ph = Whh + (size_t)(g * H_ + c0h + j) * H_ + kc * KCW;
            #pragma unroll
            for (int q = 0; q < 19; ++q) {
                float4 v = *(const float4*)(ph + 4 * q);
                v2f a; a.x = v.x; a.y = v.y;
                v2f b; b.x = v.z; b.y = v.w;
                wh2[2 * q] = a; wh2[2 * q + 1] = b;
            }
        }
    };

    load_wi(eWih);
    load_wh(eWhh);
    // biases for BOTH phases staged once (no mid-run overwrite)
    if (tid < GC) {
        int g = tid / CBH, j = tid - (tid / CBH) * CBH;
        bi_l[0][tid] = ebih[g * H_ + c0h + j];
        bh_l[0][tid] = ebhh[g * H_ + c0h + j];
        bi_l[1][tid] = dbih[g * H_ + c0h + j];
        bh_l[1][tid] = dbhh[g * H_ + c0h + j];
    }

    // ---- prologue: hs = 0 (=h(0)); xs = x(0) ----
    {
        const ull* xin = (const ull*)input;
        #pragma unroll
        for (int i = 0; i < 5; ++i) {
            int f = tid + 256 * i;
            if (i < 4 || f < BLK_ULL) {
                int rr = f / HW, q = f - (f / HW) * HW;
                ((ull*)xs)[f] = xin[(size_t)(r0 + rr) * T_ * HW + q];
                ((ull*)hs)[f] = 0ull;
            }
        }
    }
    __syncthreads();
    // gi(0) -> red0
    if (act) {
        #pragma unroll 4
        for (int rr = 0; rr < RB; ++rr) {
            v2f a0 = {0.f, 0.f}, a1 = {0.f, 0.f};
            #pragma unroll
            for (int q = 0; q < 19; ++q) {
                float4 xv = *(const float4*)&xs[rr][kc * KCW + 4 * q];
                v2f lo; lo.x = xv.x; lo.y = xv.y;
                v2f hi; hi.x = xv.z; hi.y = xv.w;
                a0 = __builtin_elementwise_fma(lo, wi2[2 * q],     a0);
                a1 = __builtin_elementwise_fma(hi, wi2[2 * q + 1], a1);
            }
            v2f a = a0 + a1;
            RED(0, kc, lane, rr) = a.x + a.y;
        }
    }
    // xr <- x(1)
    ull xr[5];
    {
        const ull* xin = (const ull*)input;
        #pragma unroll
        for (int i = 0; i < 5; ++i) {
            int f = tid + 256 * i;
            if (i < 4 || f < BLK_ULL) {
                int rr = f / HW, q = f - (f / HW) * HW;
                xr[i] = xin[((size_t)(r0 + rr) * T_ + 1) * HW + q];
            }
        }
    }

    for (int s = 0; s < NSTEP; ++s) {
        __syncthreads();   // top: releases from tid0 spin; red0(gi s) ready
        const bool enc = (s < T_);
        if (s == T_) load_wh(dWhh);            // private regs, race-free

        // ---- issue h(s) loads (XCD-local MALL) ----
        ull hreg[5];
        if (s > 0) {
            const ull* hsrc = (const ull*)(hbuf + (size_t)(s & 1) * (B_ * H_))
                              + (size_t)r0 * HW;
            #pragma unroll
            for (int i = 0; i < 5; ++i) {
                int f = tid + 256 * i;
                if (i < 4 || f < BLK_ULL)
                    hreg[i] = __hip_atomic_load(hsrc + f, __ATOMIC_RELAXED,
                                                __HIP_MEMORY_SCOPE_AGENT);
            }
        }
        // ---- xs <- xr (= x(s+1)) ----
        if (s + 1 < NSTEP) {
            ull* xd = (ull*)xs;
            #pragma unroll
            for (int i = 0; i < 5; ++i) {
                int f = tid + 256 * i;
                if (i < 4 || f < BLK_ULL) xd[f] = xr[i];
            }
        }
        // ---- issue xr <- x(s+2) ----
        if (s + 2 < NSTEP) {
            if (s + 2 < T_) {
                const ull* xin = (const ull*)input;
                #pragma unroll
                for (int i = 0; i < 5; ++i) {
                    int f = tid + 256 * i;
                    if (i < 4 || f < BLK_ULL) {
                        int rr = f / HW, q = f - (f / HW) * HW;
                        xr[i] = xin[((size_t)(r0 + rr) * T_ + (s + 2)) * HW + q];
                    }
                }
            } else {
                const ull* eb = (const ull*)emb;
                int p2 = s + 2 - T_;
                #pragma unroll
                for (int i = 0; i < 5; ++i) {
                    int f = tid + 256 * i;
                    if (i < 4 || f < BLK_ULL) {
                        int rr = f / HW, q = f - (f / HW) * HW;
                        int tok = (p2 == 0) ? 0 : target[(r0 + rr) * P_ + p2];
                        xr[i] = eb[(size_t)tok * HW + q];
                    }
                }
            }
        }
        // ---- hs <- hreg ----
        if (s > 0) {
            ull* hd = (ull*)hs;
            #pragma unroll
            for (int i = 0; i < 5; ++i) {
                int f = tid + 256 * i;
                if (i < 4 || f < BLK_ULL) hd[f] = hreg[i];
            }
        }
        __syncthreads();   // mid: hs ready

        // ---- gh GEMM: h(s) . Whh -> red1 ----
        if (act) {
            #pragma unroll 4
            for (int rr = 0; rr < RB; ++rr) {
                v2f a0 = {0.f, 0.f}, a1 = {0.f, 0.f};
                #pragma unroll
                for (int q = 0; q < 19; ++q) {
                    float4 hv = *(const float4*)&hs[rr][kc * KCW + 4 * q];
                    v2f lo; lo.x = hv.x; lo.y = hv.y;
                    v2f hi; hi.x = hv.z; hi.y = hv.w;
                    a0 = __builtin_elementwise_fma(lo, wh2[2 * q],     a0);
                    a1 = __builtin_elementwise_fma(hi, wh2[2 * q + 1], a1);
                }
                v2f a = a0 + a1;
                RED(1, kc, lane, rr) = a.x + a.y;
            }
        }
        __syncthreads();   // red-ready

        // ---- gates -> h(s+1) ----
        float* hdst = hbuf + (size_t)((s + 1) & 1) * (B_ * H_);
        if (tid < RB * CBH) {
            int rr = tid / CBH, j = tid - (tid / CBH) * CBH;
            int col = c0h + j;
            int ph = enc ? 0 : 1;
            float Gi[3], Gh[3];
            #pragma unroll
            for (int g = 0; g < 3; ++g) {
                int cc = g * CBH + j;
                Gi[g] = RED(0, 0, cc, rr) + RED(0, 1, cc, rr) +
                        RED(0, 2, cc, rr) + RED(0, 3, cc, rr) + bi_l[ph][cc];
                Gh[g] = RED(1, 0, cc, rr) + RED(1, 1, cc, rr) +
                        RED(1, 2, cc, rr) + RED(1, 3, cc, rr) + bh_l[ph][cc];
            }
            float rg = 1.f / (1.f + expf(-(Gi[0] + Gh[0])));
            float zg = 1.f / (1.f + expf(-(Gi[1] + Gh[1])));
            float ng = tanhf(Gi[2] + rg * Gh[2]);
            float hnew = (1.f - zg) * ng + zg * hs[rr][col];
            __hip_atomic_store(&hdst[(size_t)(r0 + rr) * H_ + col], hnew,
                               __ATOMIC_RELAXED, __HIP_MEMORY_SCOPE_AGENT);
            if (!enc)
                dec_outs[((size_t)(r0 + rr) * PD + (s - T_)) * H_ + col] = hnew;
        }
        __syncthreads();   // drain: h stores flushed (vmcnt 0); red0 free

        if (s + 1 < NSTEP) {
            if (tid == 0)
                __hip_atomic_fetch_add(ctrp, 1, __ATOMIC_RELAXED,
                                       __HIP_MEMORY_SCOPE_AGENT);
            if (s + 1 == T_) load_wi(dWih);    // private regs, race-free
            // ---- gi(s+1): x(s+1) . Wih -> red0  (overlaps peer skew) ----
            if (act) {
                #pragma unroll 4
                for (int rr = 0; rr < RB; ++rr) {
                    v2f a0 = {0.f, 0.f}, a1 = {0.f, 0.f};
                    #pragma unroll
                    for (int q = 0; q < 19; ++q) {
                        float4 xv = *(const float4*)&xs[rr][kc * KCW + 4 * q];
                        v2f lo; lo.x = xv.x; lo.y = xv.y;
                        v2f hi; hi.x = xv.z; hi.y = xv.w;
                        a0 = __builtin_elementwise_fma(lo, wi2[2 * q],     a0);
                        a1 = __builtin_elementwise_fma(hi, wi2[2 * q + 1], a1);
                    }
                    v2f a = a0 + a1;
                    RED(0, kc, lane, rr) = a.x + a.y;
                }
            }
            if (tid == 0) {
                int tgt = NCB * (s + 1);
                while (__hip_atomic_load(ctrp, __ATOMIC_RELAXED,
                                         __HIP_MEMORY_SCOPE_AGENT) < tgt)
                    __builtin_amdgcn_s_sleep(1);
            }
        }
    }
}

// ---------------------------------------------------------------------------
// logits -> softmax -> (softmax_cal, target_cal, asr_outputs)
// ---------------------------------------------------------------------------
__global__ __launch_bounds__(256) void logits_softmax(
    const float* __restrict__ dec_outs,   // [B*PD][H]
    const float* __restrict__ linW,       // [61][304]
    const float* __restrict__ linb,       // [61]
    const int* __restrict__ target,       // [B][P][1]
    float* __restrict__ out)
{
    __shared__ float wsm[H_][64];   // transposed W
    __shared__ float rs[4][H_];
    const int tid = threadIdx.x;
    const int wv = tid >> 6, l = tid & 63;

    for (int f = tid; f < H_ * 64; f += 256) {
        int k = f >> 6, ll = f & 63;
        wsm[k][ll] = (ll < D_) ? linW[(size_t)ll * H_ + k] : 0.f;
    }
    const int r = blockIdx.x * 4 + wv;
    const float* rowp = dec_outs + (size_t)r * H_;
    for (int k = l; k < H_; k += 64) rs[wv][k] = rowp[k];
    __syncthreads();

    float acc = -1e30f;
    if (l < D_) {
        acc = linb[l];
        #pragma unroll 4
        for (int k = 0; k < H_; ++k) acc += rs[wv][k] * wsm[k][l];
    }
    float m = acc;
    for (int off = 32; off; off >>= 1) m = fmaxf(m, __shfl_xor(m, off));
    float e = (l < D_) ? expf(acc - m) : 0.f;
    float s = e;
    for (int off = 32; off; off >>= 1) s += __shfl_xor(s, off);
    float av = acc; int ai = l;
    for (int off = 32; off; off >>= 1) {
        float ov = __shfl_xor(av, off);
        int oi = __shfl_xor(ai, off);
        if (ov > av || (ov == av && oi < ai)) { av = ov; ai = oi; }
    }
    const int b = r / PD, p = r - (r / PD) * PD;
    const size_t OFF1 = (size_t)B_ * PD * D_;
    const size_t OFF2 = OFF1 + (size_t)B_ * PD;
    if (l < D_)        out[(size_t)r * D_ + l] = e / s;
    else if (l == D_)  out[OFF1 + r] = (float)target[b * P_ + p + 1];
    else if (l == D_ + 1) out[OFF2 + r] = (float)ai;
}

// ---------------------------------------------------------------------------
extern "C" void kernel_launch(void* const* d_in, const int* in_sizes, int n_in,
                              void* d_out, int out_size, void* d_ws, size_t ws_size,
                              hipStream_t stream)
{
    const float* input  = (const float*)d_in[0];
    const int*   target = (const int*)d_in[1];
    const float* eWih = (const float*)d_in[3];
    const float* eWhh = (const float*)d_in[4];
    const float* ebih = (const float*)d_in[5];
    const float* ebhh = (const float*)d_in[6];
    const float* emb  = (const float*)d_in[7];
    const float* dWih = (const float*)d_in[8];
    const float* dWhh = (const float*)d_in[9];
    const float* dbih = (const float*)d_in[10];
    const float* dbhh = (const float*)d_in[11];
    const float* linW = (const float*)d_in[12];
    const float* linb = (const float*)d_in[13];
    float* out = (float*)d_out;

    int*   ctr      = (int*)d_ws;                    // NBG*32 ints (4 KB)
    float* hbuf     = (float*)d_ws + 1024;           // 2 * B*H
    float* dec_outs = hbuf + 2 * (size_t)B_ * H_;    // B*PD*H

    (void)hipMemsetAsync(ctr, 0, 1024 * sizeof(int), stream);

    gru_persist<<<dim3(NCB, NBG), 256, 0, stream>>>(
        input, target, emb,
        eWih, eWhh, ebih, ebhh,
        dWih, dWhh, dbih, dbhh,
        hbuf, dec_outs, ctr);

    logits_softmax<<<dim3(B_ * PD / 4), 256, 0, stream>>>(
        dec_outs, linW, linb, target, out);
}

// Round 8
// 6450.608 us; speedup vs baseline: 2.2211x; 1.0525x over previous
//
#include <hip/hip_runtime.h>
#include <math.h>

#define B_   256
#define E_   304
#define H_   304
#define T_   512
#define P_   68
#define PD   67      // decoder output positions
#define D_   61
#define NCB  16      // col-blocks per batch group
#define NBG  32      // batch groups
#define RB   8       // rows (batch) per block
#define CBH  19      // h-cols per block
#define GC   57      // gate-cols per block (3*19)
#define NSTEP (T_ + PD)
#define HW   152     // ull words per f32 row (304 floats)
#define BLK_ULL (RB * HW)   // 1216
#define LROW 328     // padded f16 row length (K 320 + pad; stride 656B: 16B-aligned, conflict-spread)
#define LROWU 164    // u32 (f16-pair) words per row
#define NKS  10      // K-steps of 32 (K padded 304->320)
#define SC_LO 2048.0f
#define SC_INV 4.8828125e-4f   // 2^-11

typedef unsigned long long ull;
typedef _Float16 half8 __attribute__((ext_vector_type(8)));
typedef _Float16 half2v __attribute__((ext_vector_type(2)));
typedef float f32x4 __attribute__((ext_vector_type(4)));

// ---------------------------------------------------------------------------
// Persistent GRU via split-f16 MFMA. Grid (16,32)=512 blocks, 256 thr, 2/CU.
// XCD-local groups (L%8 swizzle). Block (cb,bg): rows r0=bg*8..+7, h-cols
// c0h=cb*19..+18 (57 gate-cols, padded to 64 = 4 MFMA col-tiles).
// Wave wv owns col-tile wv (cols wv*16..+15); lane l holds B-fragment
// weights (col = wv*16 + (l&15), k-slice 8*(l>>4)+j per K-step) for Wih+Whh
// in 2-way f16 split (hi + 2^-11*lo', lo' prescaled x2048): 160 u32 regs,
// persistent (AGPR-resident; MFMA reads AGPRs directly).
// x/h staged in LDS as f16 hi/lo arrays [9][328] (row 8 = shared zero row for
// M-padding 8->16; k 304..319 zero). Per GEMM per wave: 20 ds_read_b128
// (per-lane distinct - no broadcast amplification) + 30 MFMA.
// Exact-enough: error ~2^-22 rel (argmax-safe, matches f32 kernel family).
// Sync/exchange/barrier structure identical to R5/R7 (proven).
// ---------------------------------------------------------------------------
__global__ __launch_bounds__(256, 2) void gru_persist(
    const float* __restrict__ input,   // [B][T][E]
    const int*   __restrict__ target,  // [B][P]
    const float* __restrict__ emb,     // [D][E]
    const float* __restrict__ eWih, const float* __restrict__ eWhh,
    const float* __restrict__ ebih, const float* __restrict__ ebhh,
    const float* __restrict__ dWih, const float* __restrict__ dWhh,
    const float* __restrict__ dbih, const float* __restrict__ dbhh,
    float* hbuf,                       // [2][B*H]
    float* __restrict__ dec_outs,      // [(b*PD+p)*H]
    int* ctr)                          // [NBG*32]
{
    __shared__ _Float16 opH[2][9 * LROW];   // [0]=x, [1]=h  (hi parts)
    __shared__ _Float16 opL[2][9 * LROW];   // lo' parts (x2048)
    __shared__ float red0[64 * 9], red1[64 * 9];
    __shared__ float bi_l[2][GC], bh_l[2][GC];

    const int tid  = threadIdx.x;
    const int L    = blockIdx.y * NCB + blockIdx.x;   // 0..511
    const int xcd  = L & 7;
    const int yy   = L >> 3;
    const int cb   = yy & 15;                          // 0..15
    const int bg   = ((yy >> 4) << 3) | xcd;           // 0..31, group on one XCD
    const int r0   = bg * RB;
    const int c0h  = cb * CBH;
    const int wv   = tid >> 6;         // wave id = col-tile
    const int lane = tid & 63;
    int* ctrp = ctr + bg * 32;

    half8 wih_h[NKS], wih_l[NKS], whh_h[NKS], whh_l[NKS];

    // ---- pack weights into B-fragments (per lane: col wv*16+(l&15)) ----
    auto packw = [&](const float* W, half8* wh, half8* wl) {
        int c = wv * 16 + (lane & 15);
        bool valid = (c < GC);
        int g = valid ? c / CBH : 0, j19 = valid ? c - (c / CBH) * CBH : 0;
        const float* wp = W + (size_t)(g * H_ + c0h + j19) * 304;
        int grp = (lane >> 4) * 8;
        #pragma unroll
        for (int ks = 0; ks < NKS; ++ks) {
            half8 vh, vl;
            #pragma unroll
            for (int j = 0; j < 8; ++j) {
                int k = ks * 32 + grp + j;
                float v = (valid && k < 304) ? wp[k] : 0.f;
                _Float16 hi = (_Float16)v;
                float rres = v - (float)hi;
                vh[j] = hi;
                vl[j] = (_Float16)(rres * SC_LO);
            }
            wh[ks] = vh; wl[ks] = vl;
        }
    };

    // ---- GEMM: red[col][row] = A(16x320) . B(320x16), 3-term split ----
    auto gemm = [&](const _Float16* aH, const _Float16* aL,
                    const half8* wh, const half8* wl, float* red) {
        const int r16 = lane & 15;
        const int rcl = (r16 < 8) ? r16 : 8;       // rows 8..15 -> zero row 8
        const int base = rcl * LROW + (lane >> 4) * 8;
        f32x4 a0 = {0.f, 0.f, 0.f, 0.f}, a1 = a0, a2 = a0;
        #pragma unroll
        for (int ks = 0; ks < NKS; ++ks) {
            half8 Ah = *(const half8*)&aH[base + ks * 32];
            half8 Al = *(const half8*)&aL[base + ks * 32];
            a0 = __builtin_amdgcn_mfma_f32_16x16x32_f16(Ah, wh[ks], a0, 0, 0, 0);
            a1 = __builtin_amdgcn_mfma_f32_16x16x32_f16(Ah, wl[ks], a1, 0, 0, 0);
            a2 = __builtin_amdgcn_mfma_f32_16x16x32_f16(Al, wh[ks], a2, 0, 0, 0);
        }
        f32x4 r = a0 + (a1 + a2) * SC_INV;
        if (lane < 32) {                           // rows 0..7 only
            int rb = (wv * 16 + r16) * 9 + (lane >> 4) * 4;
            #pragma unroll
            for (int i = 0; i < 4; ++i) red[rb + i] = r[i];
        }
    };

    // ---- convert ull (2 f32) -> hi-pair + lo-pair, store to LDS ----
    auto cvtstore = [&](ull u, int plane, int idx) {
        float a0 = __uint_as_float((unsigned)u);
        float a1 = __uint_as_float((unsigned)(u >> 32));
        _Float16 h0 = (_Float16)a0, h1 = (_Float16)a1;
        float r0f = a0 - (float)h0, r1f = a1 - (float)h1;
        half2v vh; vh.x = h0; vh.y = h1;
        half2v vl; vl.x = (_Float16)(r0f * SC_LO); vl.y = (_Float16)(r1f * SC_LO);
        ((half2v*)&opH[plane][0])[idx] = vh;
        ((half2v*)&opL[plane][0])[idx] = vl;
    };

    packw(eWih, wih_h, wih_l);
    packw(eWhh, whh_h, whh_l);
    if (tid < GC) {
        int g = tid / CBH, j = tid - (tid / CBH) * CBH;
        bi_l[0][tid] = ebih[g * H_ + c0h + j];
        bh_l[0][tid] = ebhh[g * H_ + c0h + j];
        bi_l[1][tid] = dbih[g * H_ + c0h + j];
        bh_l[1][tid] = dbhh[g * H_ + c0h + j];
    }

    // ---- prologue: zero f16 arrays (rows 8 + k-tails stay zero forever) ----
    for (int f = tid; f < 9 * LROW; f += 256) {   // covers both planes via u32
        ((unsigned*)opH)[f] = 0u;                  // 2*9*LROW f16 = 9*LROW u32
        ((unsigned*)opL)[f] = 0u;
    }
    __syncthreads();
    // stage x(0)
    {
        const ull* xin = (const ull*)input;
        #pragma unroll
        for (int i = 0; i < 5; ++i) {
            int f = tid + 256 * i;
            if (i < 4 || f < BLK_ULL) {
                int rr = f / HW, q = f - (f / HW) * HW;
                cvtstore(xin[(size_t)(r0 + rr) * T_ * HW + q], 0, rr * LROWU + q);
            }
        }
    }
    __syncthreads();
    gemm(opH[0], opL[0], wih_h, wih_l, red0);      // gi(0)
    // xr <- x(1)
    ull xr[5];
    {
        const ull* xin = (const ull*)input;
        #pragma unroll
        for (int i = 0; i < 5; ++i) {
            int f = tid + 256 * i;
            if (i < 4 || f < BLK_ULL) {
                int rr = f / HW, q = f - (f / HW) * HW;
                xr[i] = xin[((size_t)(r0 + rr) * T_ + 1) * HW + q];
            }
        }
    }

    for (int s = 0; s < NSTEP; ++s) {
        __syncthreads();   // top: releases from tid0 spin; red0(gi s) ready
        const bool enc = (s < T_);
        if (s == T_) packw(dWhh, whh_h, whh_l);    // private regs, race-free

        // ---- load h(s), convert -> op[1] ----
        if (s > 0) {
            const ull* hsrc = (const ull*)(hbuf + (size_t)(s & 1) * (B_ * H_))
                              + (size_t)r0 * HW;
            ull hreg[5];
            #pragma unroll
            for (int i = 0; i < 5; ++i) {
                int f = tid + 256 * i;
                if (i < 4 || f < BLK_ULL)
                    hreg[i] = __hip_atomic_load(hsrc + f, __ATOMIC_RELAXED,
                                                __HIP_MEMORY_SCOPE_AGENT);
            }
            #pragma unroll
            for (int i = 0; i < 5; ++i) {
                int f = tid + 256 * i;
                if (i < 4 || f < BLK_ULL) {
                    int rr = f / HW, q = f - (f / HW) * HW;
                    cvtstore(hreg[i], 1, rr * LROWU + q);
                }
            }
        }
        // ---- stage x(s+1) from xr -> op[0] ----
        if (s + 1 < NSTEP) {
            #pragma unroll
            for (int i = 0; i < 5; ++i) {
                int f = tid + 256 * i;
                if (i < 4 || f < BLK_ULL) {
                    int rr = f / HW, q = f - (f / HW) * HW;
                    cvtstore(xr[i], 0, rr * LROWU + q);
                }
            }
        }
        // ---- issue xr <- x(s+2) ----
        if (s + 2 < NSTEP) {
            if (s + 2 < T_) {
                const ull* xin = (const ull*)input;
                #pragma unroll
                for (int i = 0; i < 5; ++i) {
                    int f = tid + 256 * i;
                    if (i < 4 || f < BLK_ULL) {
                        int rr = f / HW, q = f - (f / HW) * HW;
                        xr[i] = xin[((size_t)(r0 + rr) * T_ + (s + 2)) * HW + q];
                    }
                }
            } else {
                const ull* eb = (const ull*)emb;
                int p2 = s + 2 - T_;
                #pragma unroll
                for (int i = 0; i < 5; ++i) {
                    int f = tid + 256 * i;
                    if (i < 4 || f < BLK_ULL) {
                        int rr = f / HW, q = f - (f / HW) * HW;
                        int tok = (p2 == 0) ? 0 : target[(r0 + rr) * P_ + p2];
                        xr[i] = eb[(size_t)tok * HW + q];
                    }
                }
            }
        }
        __syncthreads();   // mid: op[1] (h) ready

        // ---- gh GEMM: h(s) . Whh^T -> red1 ----
        gemm(opH[1], opL[1], whh_h, whh_l, red1);
        __syncthreads();   // red-ready

        // ---- gates -> h(s+1) ----
        float* hdst = hbuf + (size_t)((s + 1) & 1) * (B_ * H_);
        if (tid < RB * CBH) {
            int rr = tid / CBH, j = tid - (tid / CBH) * CBH;
            int col = c0h + j;
            int ph = enc ? 0 : 1;
            float Gi[3], Gh[3];
            #pragma unroll
            for (int g = 0; g < 3; ++g) {
                int c = g * CBH + j;
                Gi[g] = red0[c * 9 + rr] + bi_l[ph][c];
                Gh[g] = red1[c * 9 + rr] + bh_l[ph][c];
            }
            float rg = 1.f / (1.f + expf(-(Gi[0] + Gh[0])));
            float zg = 1.f / (1.f + expf(-(Gi[1] + Gh[1])));
            float ng = tanhf(Gi[2] + rg * Gh[2]);
            float hv = (float)opH[1][rr * LROW + col]
                     + (float)opL[1][rr * LROW + col] * SC_INV;
            float hnew = (1.f - zg) * ng + zg * hv;
            __hip_atomic_store(&hdst[(size_t)(r0 + rr) * H_ + col], hnew,
                               __ATOMIC_RELAXED, __HIP_MEMORY_SCOPE_AGENT);
            if (!enc)
                dec_outs[((size_t)(r0 + rr) * PD + (s - T_)) * H_ + col] = hnew;
        }
        __syncthreads();   // drain: h stores flushed; red0 free

        if (s + 1 < NSTEP) {
            if (tid == 0)
                __hip_atomic_fetch_add(ctrp, 1, __ATOMIC_RELAXED,
                                       __HIP_MEMORY_SCOPE_AGENT);
            if (s + 1 == T_) packw(dWih, wih_h, wih_l);
            // ---- gi(s+1): x(s+1) . Wih^T -> red0 (overlaps peer skew) ----
            gemm(opH[0], opL[0], wih_h, wih_l, red0);
            if (tid == 0) {
                int tgt = NCB * (s + 1);
                while (__hip_atomic_load(ctrp, __ATOMIC_RELAXED,
                                         __HIP_MEMORY_SCOPE_AGENT) < tgt)
                    __builtin_amdgcn_s_sleep(1);
            }
        }
    }
}

// ---------------------------------------------------------------------------
// logits -> softmax -> (softmax_cal, target_cal, asr_outputs)
// ---------------------------------------------------------------------------
__global__ __launch_bounds__(256) void logits_softmax(
    const float* __restrict__ dec_outs,   // [B*PD][H]
    const float* __restrict__ linW,       // [61][304]
    const float* __restrict__ linb,       // [61]
    const int* __restrict__ target,       // [B][P][1]
    float* __restrict__ out)
{
    __shared__ float wsm[H_][64];   // transposed W
    __shared__ float rs[4][H_];
    const int tid = threadIdx.x;
    const int wv = tid >> 6, l = tid & 63;

    for (int f = tid; f < H_ * 64; f += 256) {
        int k = f >> 6, ll = f & 63;
        wsm[k][ll] = (ll < D_) ? linW[(size_t)ll * H_ + k] : 0.f;
    }
    const int r = blockIdx.x * 4 + wv;
    const float* rowp = dec_outs + (size_t)r * H_;
    for (int k = l; k < H_; k += 64) rs[wv][k] = rowp[k];
    __syncthreads();

    float acc = -1e30f;
    if (l < D_) {
        acc = linb[l];
        #pragma unroll 4
        for (int k = 0; k < H_; ++k) acc += rs[wv][k] * wsm[k][l];
    }
    float m = acc;
    for (int off = 32; off; off >>= 1) m = fmaxf(m, __shfl_xor(m, off));
    float e = (l < D_) ? expf(acc - m) : 0.f;
    float s = e;
    for (int off = 32; off; off >>= 1) s += __shfl_xor(s, off);
    float av = acc; int ai = l;
    for (int off = 32; off; off >>= 1) {
        float ov = __shfl_xor(av, off);
        int oi = __shfl_xor(ai, off);
        if (ov > av || (ov == av && oi < ai)) { av = ov; ai = oi; }
    }
    const int b = r / PD, p = r - (r / PD) * PD;
    const size_t OFF1 = (size_t)B_ * PD * D_;
    const size_t OFF2 = OFF1 + (size_t)B_ * PD;
    if (l < D_)        out[(size_t)r * D_ + l] = e / s;
    else if (l == D_)  out[OFF1 + r] = (float)target[b * P_ + p + 1];
    else if (l == D_ + 1) out[OFF2 + r] = (float)ai;
}

// ---------------------------------------------------------------------------
extern "C" void kernel_launch(void* const* d_in, const int* in_sizes, int n_in,
                              void* d_out, int out_size, void* d_ws, size_t ws_size,
                              hipStream_t stream)
{
    const float* input  = (const float*)d_in[0];
    const int*   target = (const int*)d_in[1];
    const float* eWih = (const float*)d_in[3];
    const float* eWhh = (const float*)d_in[4];
    const float* ebih = (const float*)d_in[5];
    const float* ebhh = (const float*)d_in[6];
    const float* emb  = (const float*)d_in[7];
    const float* dWih = (const float*)d_in[8];
    const float* dWhh = (const float*)d_in[9];
    const float* dbih = (const float*)d_in[10];
    const float* dbhh = (const float*)d_in[11];
    const float* linW = (const float*)d_in[12];
    const float* linb = (const float*)d_in[13];
    float* out = (float*)d_out;

    int*   ctr      = (int*)d_ws;                    // NBG*32 ints (4 KB)
    float* hbuf     = (float*)d_ws + 1024;           // 2 * B*H
    float* dec_outs = hbuf + 2 * (size_t)B_ * H_;    // B*PD*H

    (void)hipMemsetAsync(ctr, 0, 1024 * sizeof(int), stream);

    gru_persist<<<dim3(NCB, NBG), 256, 0, stream>>>(
        input, target, emb,
        eWih, eWhh, ebih, ebhh,
        dWih, dWhh, dbih, dbhh,
        hbuf, dec_outs, ctr);

    logits_softmax<<<dim3(B_ * PD / 4), 256, 0, stream>>>(
        dec_outs, linW, linb, target, out);
}

// Round 9
// 2389.999 us; speedup vs baseline: 5.9947x; 2.6990x over previous
//
#include <hip/hip_runtime.h>
#include <math.h>

#define B_   256
#define E_   304
#define H_   304
#define T_   512
#define P_   68
#define PD   67      // decoder output positions
#define D_   61
#define NCB  16      // col-blocks per batch group
#define NBG  16      // batch groups
#define RB   16      // rows (batch) per block -- full MFMA M dim
#define CBH  19      // h-cols per block
#define GC   57      // gate-cols per block (3*19)
#define NSTEP (T_ + PD)
#define HW   152     // ull words per f32 row (304 floats)
#define BLK_ULL (RB * HW)   // 2432
#define LROW 328     // padded f16 row length (K 320 + pad)
#define LROWU 164    // u32 (f16-pair) words per row
#define NKS  10      // K-steps of 32 (K padded 304->320)
#define SC_LO 2048.0f
#define SC_INV 4.8828125e-4f   // 2^-11

typedef unsigned long long ull;
typedef _Float16 half8 __attribute__((ext_vector_type(8)));
typedef _Float16 half2v __attribute__((ext_vector_type(2)));
typedef float f32x4 __attribute__((ext_vector_type(4)));

// ---------------------------------------------------------------------------
// Persistent GRU via split-f16 MFMA. Grid 256 blocks, 256 thr, 1 block/CU
// (no co-resident cross-group interference). XCD-local groups (L%8 swizzle,
// 2 groups per XCD). Block (cb,bg): rows r0=bg*16..+15 (full M=16 MFMA tile,
// no padding), h-cols c0h=cb*19..+18 (57 gate-cols in 4 MFMA col-tiles).
// Wave wv owns col-tile wv; lane l holds B-fragment weights for Wih+Whh in
// 2-way f16 split (hi + 2^-11*lo', lo' prescaled x2048): 160 u32 regs.
// x/h staged in LDS as f16 hi/lo [16][328] (k 304..319 zero).
// Step order: spin | issue h loads | stage x(s+1) (hides MALL latency) |
// cvt h | sync | gh MFMA | sync | gates -> h(s+1) agent-store | drain-sync |
// tid0 arrive | gi(s+1) MFMA (hides peer skew) | tid0 spin | top-sync.
// ---------------------------------------------------------------------------
__global__ __launch_bounds__(256, 1) void gru_persist(
    const float* __restrict__ input,   // [B][T][E]
    const int*   __restrict__ target,  // [B][P]
    const float* __restrict__ emb,     // [D][E]
    const float* __restrict__ eWih, const float* __restrict__ eWhh,
    const float* __restrict__ ebih, const float* __restrict__ ebhh,
    const float* __restrict__ dWih, const float* __restrict__ dWhh,
    const float* __restrict__ dbih, const float* __restrict__ dbhh,
    float* hbuf,                       // [2][B*H]
    float* __restrict__ dec_outs,      // [(b*PD+p)*H]
    int* ctr)                          // [NBG*32]
{
    __shared__ _Float16 opH[2][RB * LROW];   // [0]=x, [1]=h  (hi parts)
    __shared__ _Float16 opL[2][RB * LROW];   // lo' parts (x2048)
    __shared__ float red0[64 * 17], red1[64 * 17];
    __shared__ float bi_l[2][GC], bh_l[2][GC];

    const int tid  = threadIdx.x;
    const int L    = blockIdx.x;       // 0..255
    const int xcd  = L & 7;
    const int yy   = L >> 3;
    const int cb   = yy & 15;                          // 0..15
    const int bg   = ((yy >> 4) << 3) | xcd;           // 0..15, group on one XCD
    const int r0   = bg * RB;
    const int c0h  = cb * CBH;
    const int wv   = tid >> 6;         // wave id = col-tile
    const int lane = tid & 63;
    int* ctrp = ctr + bg * 32;

    half8 wih_h[NKS], wih_l[NKS], whh_h[NKS], whh_l[NKS];

    // ---- pack weights into B-fragments (per lane: col wv*16+(l&15)) ----
    auto packw = [&](const float* W, half8* wh, half8* wl) {
        int c = wv * 16 + (lane & 15);
        bool valid = (c < GC);
        int g = valid ? c / CBH : 0, j19 = valid ? c - (c / CBH) * CBH : 0;
        const float* wp = W + (size_t)(g * H_ + c0h + j19) * 304;
        int grp = (lane >> 4) * 8;
        #pragma unroll
        for (int ks = 0; ks < NKS; ++ks) {
            half8 vh, vl;
            #pragma unroll
            for (int j = 0; j < 8; ++j) {
                int k = ks * 32 + grp + j;
                float v = (valid && k < 304) ? wp[k] : 0.f;
                _Float16 hi = (_Float16)v;
                float rres = v - (float)hi;
                vh[j] = hi;
                vl[j] = (_Float16)(rres * SC_LO);
            }
            wh[ks] = vh; wl[ks] = vl;
        }
    };

    // ---- GEMM: red[col*17+row] = A(16x320) . B(320x16), 3-term split ----
    auto gemm = [&](const _Float16* aH, const _Float16* aL,
                    const half8* wh, const half8* wl, float* red) {
        const int base = (lane & 15) * LROW + (lane >> 4) * 8;
        f32x4 a0 = {0.f, 0.f, 0.f, 0.f}, a1 = a0, a2 = a0;
        #pragma unroll
        for (int ks = 0; ks < NKS; ++ks) {
            half8 Ah = *(const half8*)&aH[base + ks * 32];
            half8 Al = *(const half8*)&aL[base + ks * 32];
            a0 = __builtin_amdgcn_mfma_f32_16x16x32_f16(Ah, wh[ks], a0, 0, 0, 0);
            a1 = __builtin_amdgcn_mfma_f32_16x16x32_f16(Ah, wl[ks], a1, 0, 0, 0);
            a2 = __builtin_amdgcn_mfma_f32_16x16x32_f16(Al, wh[ks], a2, 0, 0, 0);
        }
        f32x4 r = a0 + (a1 + a2) * SC_INV;
        // C layout: col = lane&15 (within tile wv), row = (lane>>4)*4 + i
        int rb = (wv * 16 + (lane & 15)) * 17 + (lane >> 4) * 4;
        #pragma unroll
        for (int i = 0; i < 4; ++i) red[rb + i] = r[i];
    };

    // ---- convert ull (2 f32) -> hi-pair + lo-pair, store to LDS ----
    auto cvtstore = [&](ull u, int plane, int idx) {
        float a0 = __uint_as_float((unsigned)u);
        float a1 = __uint_as_float((unsigned)(u >> 32));
        _Float16 h0 = (_Float16)a0, h1 = (_Float16)a1;
        float r0f = a0 - (float)h0, r1f = a1 - (float)h1;
        half2v vh; vh.x = h0; vh.y = h1;
        half2v vl; vl.x = (_Float16)(r0f * SC_LO); vl.y = (_Float16)(r1f * SC_LO);
        ((half2v*)&opH[plane][0])[idx] = vh;
        ((half2v*)&opL[plane][0])[idx] = vl;
    };

    packw(eWih, wih_h, wih_l);
    packw(eWhh, whh_h, whh_l);
    if (tid < GC) {
        int g = tid / CBH, j = tid - (tid / CBH) * CBH;
        bi_l[0][tid] = ebih[g * H_ + c0h + j];
        bh_l[0][tid] = ebhh[g * H_ + c0h + j];
        bi_l[1][tid] = dbih[g * H_ + c0h + j];
        bh_l[1][tid] = dbhh[g * H_ + c0h + j];
    }

    // ---- prologue: zero f16 arrays (k-tails 304..319 + pad stay zero) ----
    for (int f = tid; f < RB * LROW; f += 256) {   // RB*LROW u32 covers both planes
        ((unsigned*)opH)[f] = 0u;
        ((unsigned*)opL)[f] = 0u;
    }
    __syncthreads();
    // stage x(0)
    {
        const ull* xin = (const ull*)input;
        #pragma unroll
        for (int i = 0; i < 10; ++i) {
            int f = tid + 256 * i;
            if (i < 9 || f < BLK_ULL) {
                int rr = f / HW, q = f - (f / HW) * HW;
                cvtstore(xin[(size_t)(r0 + rr) * T_ * HW + q], 0, rr * LROWU + q);
            }
        }
    }
    __syncthreads();
    gemm(opH[0], opL[0], wih_h, wih_l, red0);      // gi(0)
    // xr <- x(1)
    ull xr[10];
    {
        const ull* xin = (const ull*)input;
        #pragma unroll
        for (int i = 0; i < 10; ++i) {
            int f = tid + 256 * i;
            if (i < 9 || f < BLK_ULL) {
                int rr = f / HW, q = f - (f / HW) * HW;
                xr[i] = xin[((size_t)(r0 + rr) * T_ + 1) * HW + q];
            }
        }
    }

    for (int s = 0; s < NSTEP; ++s) {
        __syncthreads();   // top: releases from tid0 spin; red0(gi s) ready
        const bool enc = (s < T_);
        if (s == T_) packw(dWhh, whh_h, whh_l);    // private regs, race-free

        // ---- issue h(s) loads FIRST (MALL latency hidden by x staging) ----
        ull hreg[10];
        if (s > 0) {
            const ull* hsrc = (const ull*)(hbuf + (size_t)(s & 1) * (B_ * H_))
                              + (size_t)r0 * HW;
            #pragma unroll
            for (int i = 0; i < 10; ++i) {
                int f = tid + 256 * i;
                if (i < 9 || f < BLK_ULL)
                    hreg[i] = __hip_atomic_load(hsrc + f, __ATOMIC_RELAXED,
                                                __HIP_MEMORY_SCOPE_AGENT);
            }
        }
        // ---- stage x(s+1) from xr -> op[0] (independent VALU/LDS work) ----
        if (s + 1 < NSTEP) {
            #pragma unroll
            for (int i = 0; i < 10; ++i) {
                int f = tid + 256 * i;
                if (i < 9 || f < BLK_ULL) {
                    int rr = f / HW, q = f - (f / HW) * HW;
                    cvtstore(xr[i], 0, rr * LROWU + q);
                }
            }
        }
        // ---- convert h -> op[1] ----
        if (s > 0) {
            #pragma unroll
            for (int i = 0; i < 10; ++i) {
                int f = tid + 256 * i;
                if (i < 9 || f < BLK_ULL) {
                    int rr = f / HW, q = f - (f / HW) * HW;
                    cvtstore(hreg[i], 1, rr * LROWU + q);
                }
            }
        }
        // ---- issue xr <- x(s+2) (pure prefetch) ----
        if (s + 2 < NSTEP) {
            if (s + 2 < T_) {
                const ull* xin = (const ull*)input;
                #pragma unroll
                for (int i = 0; i < 10; ++i) {
                    int f = tid + 256 * i;
                    if (i < 9 || f < BLK_ULL) {
                        int rr = f / HW, q = f - (f / HW) * HW;
                        xr[i] = xin[((size_t)(r0 + rr) * T_ + (s + 2)) * HW + q];
                    }
                }
            } else {
                const ull* eb = (const ull*)emb;
                int p2 = s + 2 - T_;
                #pragma unroll
                for (int i = 0; i < 10; ++i) {
                    int f = tid + 256 * i;
                    if (i < 9 || f < BLK_ULL) {
                        int rr = f / HW, q = f - (f / HW) * HW;
                        int tok = (p2 == 0) ? 0 : target[(r0 + rr) * P_ + p2];
                        xr[i] = eb[(size_t)tok * HW + q];
                    }
                }
            }
        }
        __syncthreads();   // mid: op[1] (h) ready

        // ---- gh GEMM: h(s) . Whh^T -> red1 ----
        gemm(opH[1], opL[1], whh_h, whh_l, red1);
        __syncthreads();   // red-ready

        // ---- gates -> h(s+1) ----
        float* hdst = hbuf + (size_t)((s + 1) & 1) * (B_ * H_);
        for (int o = tid; o < RB * CBH; o += 256) {
            int rr = o / CBH, j = o - (o / CBH) * CBH;
            int col = c0h + j;
            int ph = enc ? 0 : 1;
            float Gi[3], Gh[3];
            #pragma unroll
            for (int g = 0; g < 3; ++g) {
                int c = g * CBH + j;
                Gi[g] = red0[c * 17 + rr] + bi_l[ph][c];
                Gh[g] = red1[c * 17 + rr] + bh_l[ph][c];
            }
            float rg = 1.f / (1.f + expf(-(Gi[0] + Gh[0])));
            float zg = 1.f / (1.f + expf(-(Gi[1] + Gh[1])));
            float ng = tanhf(Gi[2] + rg * Gh[2]);
            float hv = (float)opH[1][rr * LROW + col]
                     + (float)opL[1][rr * LROW + col] * SC_INV;
            float hnew = (1.f - zg) * ng + zg * hv;
            __hip_atomic_store(&hdst[(size_t)(r0 + rr) * H_ + col], hnew,
                               __ATOMIC_RELAXED, __HIP_MEMORY_SCOPE_AGENT);
            if (!enc)
                dec_outs[((size_t)(r0 + rr) * PD + (s - T_)) * H_ + col] = hnew;
        }
        __syncthreads();   // drain: h stores flushed (vmcnt 0); red0 free

        if (s + 1 < NSTEP) {
            if (tid == 0)
                __hip_atomic_fetch_add(ctrp, 1, __ATOMIC_RELAXED,
                                       __HIP_MEMORY_SCOPE_AGENT);
            if (s + 1 == T_) packw(dWih, wih_h, wih_l);
            // ---- gi(s+1): x(s+1) . Wih^T -> red0 (overlaps peer skew) ----
            gemm(opH[0], opL[0], wih_h, wih_l, red0);
            if (tid == 0) {
                int tgt = NCB * (s + 1);
                while (__hip_atomic_load(ctrp, __ATOMIC_RELAXED,
                                         __HIP_MEMORY_SCOPE_AGENT) < tgt)
                    __builtin_amdgcn_s_sleep(1);
            }
        }
    }
}

// ---------------------------------------------------------------------------
// logits -> softmax -> (softmax_cal, target_cal, asr_outputs)
// ---------------------------------------------------------------------------
__global__ __launch_bounds__(256) void logits_softmax(
    const float* __restrict__ dec_outs,   // [B*PD][H]
    const float* __restrict__ linW,       // [61][304]
    const float* __restrict__ linb,       // [61]
    const int* __restrict__ target,       // [B][P][1]
    float* __restrict__ out)
{
    __shared__ float wsm[H_][64];   // transposed W
    __shared__ float rs[4][H_];
    const int tid = threadIdx.x;
    const int wv = tid >> 6, l = tid & 63;

    for (int f = tid; f < H_ * 64; f += 256) {
        int k = f >> 6, ll = f & 63;
        wsm[k][ll] = (ll < D_) ? linW[(size_t)ll * H_ + k] : 0.f;
    }
    const int r = blockIdx.x * 4 + wv;
    const float* rowp = dec_outs + (size_t)r * H_;
    for (int k = l; k < H_; k += 64) rs[wv][k] = rowp[k];
    __syncthreads();

    float acc = -1e30f;
    if (l < D_) {
        acc = linb[l];
        #pragma unroll 4
        for (int k = 0; k < H_; ++k) acc += rs[wv][k] * wsm[k][l];
    }
    float m = acc;
    for (int off = 32; off; off >>= 1) m = fmaxf(m, __shfl_xor(m, off));
    float e = (l < D_) ? expf(acc - m) : 0.f;
    float s = e;
    for (int off = 32; off; off >>= 1) s += __shfl_xor(s, off);
    float av = acc; int ai = l;
    for (int off = 32; off; off >>= 1) {
        float ov = __shfl_xor(av, off);
        int oi = __shfl_xor(ai, off);
        if (ov > av || (ov == av && oi < ai)) { av = ov; ai = oi; }
    }
    const int b = r / PD, p = r - (r / PD) * PD;
    const size_t OFF1 = (size_t)B_ * PD * D_;
    const size_t OFF2 = OFF1 + (size_t)B_ * PD;
    if (l < D_)        out[(size_t)r * D_ + l] = e / s;
    else if (l == D_)  out[OFF1 + r] = (float)target[b * P_ + p + 1];
    else if (l == D_ + 1) out[OFF2 + r] = (float)ai;
}

// ---------------------------------------------------------------------------
extern "C" void kernel_launch(void* const* d_in, const int* in_sizes, int n_in,
                              void* d_out, int out_size, void* d_ws, size_t ws_size,
                              hipStream_t stream)
{
    const float* input  = (const float*)d_in[0];
    const int*   target = (const int*)d_in[1];
    const float* eWih = (const float*)d_in[3];
    const float* eWhh = (const float*)d_in[4];
    const float* ebih = (const float*)d_in[5];
    const float* ebhh = (const float*)d_in[6];
    const float* emb  = (const float*)d_in[7];
    const float* dWih = (const float*)d_in[8];
    const float* dWhh = (const float*)d_in[9];
    const float* dbih = (const float*)d_in[10];
    const float* dbhh = (const float*)d_in[11];
    const float* linW = (const float*)d_in[12];
    const float* linb = (const float*)d_in[13];
    float* out = (float*)d_out;

    int*   ctr      = (int*)d_ws;                    // NBG*32 ints
    float* hbuf     = (float*)d_ws + 1024;           // 2 * B*H
    float* dec_outs = hbuf + 2 * (size_t)B_ * H_;    // B*PD*H

    (void)hipMemsetAsync(ctr, 0, 1024 * sizeof(int), stream);

    gru_persist<<<dim3(256), 256, 0, stream>>>(
        input, target, emb,
        eWih, eWhh, ebih, ebhh,
        dWih, dWhh, dbih, dbhh,
        hbuf, dec_outs, ctr);

    logits_softmax<<<dim3(B_ * PD / 4), 256, 0, stream>>>(
        dec_outs, linW, linb, target, out);
}